// Round 3
// baseline (204.588 us; speedup 1.0000x reference)
//
#include <hip/hip_runtime.h>
#include <stdint.h>

// Problem constants: B=16, K=8, F=512, INCH=512, OUTCH=512, R=8
// rows M = B*K*F = 65536; "bk" index = b*8+k (128 slices of 512 rows)

typedef __attribute__((ext_vector_type(8))) __bf16 bf16x8;
typedef __attribute__((ext_vector_type(4))) float f32x4;
typedef __attribute__((ext_vector_type(8))) unsigned short ushort8;
typedef __attribute__((ext_vector_type(4))) unsigned short ushort4_t;
typedef __attribute__((ext_vector_type(4))) float float4_t;

#define MFMA16(a, b, c) __builtin_amdgcn_mfma_f32_16x16x32_bf16((a), (b), (c), 0, 0, 0)
#define GLL16(g, l)                                                                   \
    __builtin_amdgcn_global_load_lds((const __attribute__((address_space(1))) void*)(g), \
                                     (__attribute__((address_space(3))) void*)(l), 16, 0, 0)

__device__ inline unsigned short f2bf(float f) {
    union { float fv; unsigned u; } un; un.fv = f;
    unsigned u = un.u;
    u += 0x7FFFu + ((u >> 16) & 1u);   // RNE
    return (unsigned short)(u >> 16);
}

// fast gelu: x * sigmoid(1.5957691*(x + 0.044715 x^3)); max |err| vs exact ~2.5e-4
__device__ inline float geluf(float x) {
    float x2 = x * x;
    float inner = x + 0.044715f * x * x2;
    float e = __expf(-1.5957691216057308f * inner);
    return x * __builtin_amdgcn_rcpf(1.0f + e);
}

__device__ inline bf16x8 lds8(const unsigned short* p) {
    return __builtin_bit_cast(bf16x8, *(const ushort8*)p);
}

// ---------------- K0: all three weight mats fp32 -> bf16 in one launch ----------
__global__ void cvt_all(const float* __restrict__ a, const float* __restrict__ b,
                        const float* __restrict__ c, unsigned short* __restrict__ oa,
                        unsigned short* __restrict__ ob, unsigned short* __restrict__ oc) {
    int bid = blockIdx.x;                // 512 blocks: 128 Wp, 128 Wa, 256 Wo
    const float* s; unsigned short* d; int off;
    if (bid < 128) { s = a; d = oa; off = bid; }
    else if (bid < 256) { s = b; d = ob; off = bid - 128; }
    else { s = c; d = oc; off = bid - 256; }
    int i = off * 256 + threadIdx.x;     // float4 index
    float4_t v = *(const float4_t*)(s + (size_t)i * 4);
    ushort4_t r;
    r[0] = f2bf(v[0]); r[1] = f2bf(v[1]); r[2] = f2bf(v[2]); r[3] = f2bf(v[3]);
    *(ushort4_t*)(d + (size_t)i * 4) = r;
}

// ---------------- K1: xm = mean over K of x (fp32 out).  grid 4096 x 256 --------
__global__ void mean_x(const float* __restrict__ x, float* __restrict__ xm) {
    int gid = blockIdx.x * 256 + threadIdx.x;   // 1048576 threads
    int c  = gid & 127;          // float4 column
    int bf = gid >> 7;           // 0..8191
    int b  = bf >> 9;
    int f  = bf & 511;
    float4_t s = {0.f, 0.f, 0.f, 0.f};
#pragma unroll
    for (int k = 0; k < 8; ++k) {
        long row = (long)(b * 8 + k) * 512 + f;
        s += *(const float4_t*)(x + row * 512 + c * 4);
    }
    *(float4_t*)(xm + (long)bf * 512 + c * 4) = s * 0.125f;
}

// ------- K2/K3: O[M][256] = gelu(A_f32[M][512] @ W[256][512]^T + bias) bf16 -----
// 128x128 tile, BK=32, 4 waves, 2-phase double-buffered LDS.
// A is fp32, reg-staged (global->reg->cvt->ds_write); W bf16 via global_load_lds.
__launch_bounds__(256)
__global__ void gemm_f32a(const float* __restrict__ A,
                          const unsigned short* __restrict__ W,
                          const float* __restrict__ bias,
                          unsigned short* __restrict__ O,
                          int chunk) {                       // chunk = nwg/8
    __shared__ __align__(16) unsigned short As[2][4096];  // [128 rows][32 k]
    __shared__ __align__(16) unsigned short Bs[2][4096];  // [128 cols][32 k]
    const int tid = threadIdx.x;
    const int w = tid >> 6, l = tid & 63;
    const int wr = w >> 1, wc = w & 1;
    const int bid = blockIdx.x;
    const int work = (bid & 7) * chunk + (bid >> 3);   // bijective (nwg % 8 == 0)
    const int nt = work & 1;
    const int mt = work >> 1;
    const long row0 = (long)mt * 128;
    const int  col0 = nt * 128;

    const int sr = tid >> 1;            // staging row 0..127
    const int sk = (tid & 1) * 16;      // staging k offset
    const int lrow = l >> 2;            // GLL row within 16-row chunk
    const int lk = (l & 3) * 8;

    f32x4 acc[4][4];
    const f32x4 z4 = {0.f, 0.f, 0.f, 0.f};
#pragma unroll
    for (int i = 0; i < 4; ++i)
#pragma unroll
        for (int j = 0; j < 4; ++j) acc[i][j] = z4;

    // ---- prologue: stage tile 0 into buffer 0
    {
        const float* ap = A + (row0 + sr) * 512 + sk;
        float4_t a0 = *(const float4_t*)(ap + 0);
        float4_t a1 = *(const float4_t*)(ap + 4);
        float4_t a2 = *(const float4_t*)(ap + 8);
        float4_t a3 = *(const float4_t*)(ap + 12);
#pragma unroll
        for (int p = 0; p < 2; ++p) {
            const int c = w * 2 + p;
            GLL16(W + (long)(col0 + c * 16 + lrow) * 512 + lk, &Bs[0][c * 512]);
        }
        ushort8 w0, w1;
        w0[0] = f2bf(a0[0]); w0[1] = f2bf(a0[1]); w0[2] = f2bf(a0[2]); w0[3] = f2bf(a0[3]);
        w0[4] = f2bf(a1[0]); w0[5] = f2bf(a1[1]); w0[6] = f2bf(a1[2]); w0[7] = f2bf(a1[3]);
        w1[0] = f2bf(a2[0]); w1[1] = f2bf(a2[1]); w1[2] = f2bf(a2[2]); w1[3] = f2bf(a2[3]);
        w1[4] = f2bf(a3[0]); w1[5] = f2bf(a3[1]); w1[6] = f2bf(a3[2]); w1[7] = f2bf(a3[3]);
        *(ushort8*)&As[0][sr * 32 + sk] = w0;
        *(ushort8*)&As[0][sr * 32 + sk + 8] = w1;
    }
    __syncthreads();

    int cur = 0;
    for (int ks = 0; ks < 16; ++ks) {
        float4_t a0, a1, a2, a3;
        const bool pf = (ks < 15);
        if (pf) {
            const int k0n = (ks + 1) * 32;
            const float* ap = A + (row0 + sr) * 512 + k0n + sk;
            a0 = *(const float4_t*)(ap + 0);
            a1 = *(const float4_t*)(ap + 4);
            a2 = *(const float4_t*)(ap + 8);
            a3 = *(const float4_t*)(ap + 12);
#pragma unroll
            for (int p = 0; p < 2; ++p) {
                const int c = w * 2 + p;
                GLL16(W + (long)(col0 + c * 16 + lrow) * 512 + k0n + lk, &Bs[cur ^ 1][c * 512]);
            }
        }
        bf16x8 af[4], bfr[4];
#pragma unroll
        for (int mi = 0; mi < 4; ++mi)
            af[mi] = lds8(&As[cur][(wr * 64 + mi * 16 + (l & 15)) * 32 + (l >> 4) * 8]);
#pragma unroll
        for (int nj = 0; nj < 4; ++nj)
            bfr[nj] = lds8(&Bs[cur][(wc * 64 + nj * 16 + (l & 15)) * 32 + (l >> 4) * 8]);
#pragma unroll
        for (int mi = 0; mi < 4; ++mi)
#pragma unroll
            for (int nj = 0; nj < 4; ++nj)
                acc[mi][nj] = MFMA16(af[mi], bfr[nj], acc[mi][nj]);
        if (pf) {
            ushort8 w0, w1;
            w0[0] = f2bf(a0[0]); w0[1] = f2bf(a0[1]); w0[2] = f2bf(a0[2]); w0[3] = f2bf(a0[3]);
            w0[4] = f2bf(a1[0]); w0[5] = f2bf(a1[1]); w0[6] = f2bf(a1[2]); w0[7] = f2bf(a1[3]);
            w1[0] = f2bf(a2[0]); w1[1] = f2bf(a2[1]); w1[2] = f2bf(a2[2]); w1[3] = f2bf(a2[3]);
            w1[4] = f2bf(a3[0]); w1[5] = f2bf(a3[1]); w1[6] = f2bf(a3[2]); w1[7] = f2bf(a3[3]);
            *(ushort8*)&As[cur ^ 1][sr * 32 + sk] = w0;
            *(ushort8*)&As[cur ^ 1][sr * 32 + sk + 8] = w1;
        }
        __syncthreads();
        cur ^= 1;
    }

#pragma unroll
    for (int mi = 0; mi < 4; ++mi) {
        const long rb = row0 + wr * 64 + mi * 16 + (l >> 4) * 4;
#pragma unroll
        for (int nj = 0; nj < 4; ++nj) {
            const int cg = col0 + wc * 64 + nj * 16 + (l & 15);
            const float bv = bias[cg];
#pragma unroll
            for (int q = 0; q < 4; ++q)
                O[(rb + q) * 256 + cg] = f2bf(geluf(acc[mi][nj][q] + bv));
        }
    }
}

// ---------------- K4: z[row][r] = (h . v)/512 via MFMA, h = [hp | gy] ------------
__launch_bounds__(256)
__global__ void zcalc(const unsigned short* __restrict__ Hp,   // [65536][256]
                      const unsigned short* __restrict__ Gy,   // [8192][256]
                      const float* __restrict__ v,             // [128][512][8]
                      unsigned short* __restrict__ zb) {       // [65536][8] bf16
    __shared__ __align__(16) unsigned short As[4096];          // [128][32]
    __shared__ __align__(16) unsigned short Vt[16 * 536];      // [r 16 (8..15 zero)][i 512]
    const int tid = threadIdx.x;
    const int w = tid >> 6, l = tid & 63;
    const int mt = blockIdx.x;           // 0..511
    const long row0 = (long)mt * 128;
    const int bk = mt >> 2;
    const int bi = bk >> 3;
    const int f0 = (mt & 3) * 128;
    {
        ushort8 zz = {0, 0, 0, 0, 0, 0, 0, 0};
        for (int i = tid; i < (16 * 536) / 8; i += 256) *(ushort8*)&Vt[i * 8] = zz;
        __syncthreads();
        const float* vp = v + (long)bk * 4096;
#pragma unroll
        for (int p = 0; p < 4; ++p) {
            float4_t vv = *(const float4_t*)(vp + tid * 16 + p * 4);
#pragma unroll
            for (int j = 0; j < 4; ++j) {
                int flat = tid * 16 + p * 4 + j;   // = i*8 + r
                Vt[(flat & 7) * 536 + (flat >> 3)] = f2bf(vv[j] * (1.0f / 512.0f));
            }
        }
    }
    f32x4 zacc[2];
    const f32x4 z4 = {0.f, 0.f, 0.f, 0.f};
    zacc[0] = z4; zacc[1] = z4;
    const int lrow = l >> 2;
    const int lk = (l & 3) * 8;
    for (int ks = 0; ks < 16; ++ks) {
        const int k0 = ks * 32;
        __syncthreads();
#pragma unroll
        for (int p = 0; p < 2; ++p) {
            const int c = w * 2 + p;
            const int ar = c * 16 + lrow;
            const unsigned short* ga = (k0 < 256)
                ? Hp + (row0 + ar) * 256 + k0 + lk
                : Gy + (long)(bi * 512 + f0 + ar) * 256 + (k0 - 256) + lk;
            GLL16(ga, &As[c * 512]);
        }
        __syncthreads();
        bf16x8 bv = lds8(&Vt[(l & 15) * 536 + k0 + (l >> 4) * 8]);
#pragma unroll
        for (int q = 0; q < 2; ++q) {
            bf16x8 az = lds8(&As[((w * 2 + q) * 16 + (l & 15)) * 32 + (l >> 4) * 8]);
            zacc[q] = MFMA16(az, bv, zacc[q]);
        }
    }
    if ((l & 15) < 8) {
#pragma unroll
        for (int q = 0; q < 2; ++q) {
            const int fr = w * 2 + q;
#pragma unroll
            for (int reg = 0; reg < 4; ++reg) {
                long r = row0 + fr * 16 + (l >> 4) * 4 + reg;
                zb[r * 8 + (l & 15)] = f2bf(zacc[q][reg]);
            }
        }
    }
}

// ---------------- K5: out = gelu(h @ Wo^T + b_out + b + z.u^T/8) ----------------
// 2-phase double-buffered m97 tile; lora via one zero-padded MFMA K-step.
__launch_bounds__(256)
__global__ void gemm_out(const unsigned short* __restrict__ Hp,  // [65536][256]
                         const unsigned short* __restrict__ Gy,  // [8192][256]
                         const unsigned short* __restrict__ Wo,  // [512][512]
                         const float* __restrict__ bo,           // [512]
                         const float* __restrict__ bb,           // [16][512]
                         const float* __restrict__ u,            // [128][512][8]
                         const unsigned short* __restrict__ zb,  // [65536][8]
                         float* __restrict__ Out) {               // [65536][512]
    __shared__ __align__(16) unsigned short As[2][4096];
    __shared__ __align__(16) unsigned short Bs[2][4096];
    const int tid = threadIdx.x;
    const int w = tid >> 6, l = tid & 63;
    const int wr = w >> 1, wc = w & 1;
    const int bid = blockIdx.x;                    // 0..2047
    const int work = (bid & 7) * 256 + (bid >> 3); // XCD-chunked bijection
    const int nt = work & 3;
    const int mt = work >> 2;
    const long row0 = (long)mt * 128;
    const int bk = mt >> 2;
    const int bi = bk >> 3;
    const int f0 = (mt & 3) * 128;
    const int col0 = nt * 128;

    const int lrow = l >> 2;
    const int lk = (l & 3) * 8;

    f32x4 acc[4][4];
    const f32x4 z4 = {0.f, 0.f, 0.f, 0.f};
#pragma unroll
    for (int i = 0; i < 4; ++i)
#pragma unroll
        for (int j = 0; j < 4; ++j) acc[i][j] = z4;

    // ---- prologue: stage K-step 0 into buffer 0
#pragma unroll
    for (int p = 0; p < 2; ++p) {
        const int c = w * 2 + p;
        const int ar = c * 16 + lrow;
        GLL16(Hp + (row0 + ar) * 256 + lk, &As[0][c * 512]);
        GLL16(Wo + (long)(col0 + ar) * 512 + lk, &Bs[0][c * 512]);
    }
    __syncthreads();

    int cur = 0;
    for (int ks = 0; ks < 16; ++ks) {
        if (ks < 15) {
            const int k0n = (ks + 1) * 32;
#pragma unroll
            for (int p = 0; p < 2; ++p) {
                const int c = w * 2 + p;
                const int ar = c * 16 + lrow;
                const unsigned short* ga = (k0n < 256)
                    ? Hp + (row0 + ar) * 256 + k0n + lk
                    : Gy + (long)(bi * 512 + f0 + ar) * 256 + (k0n - 256) + lk;
                GLL16(ga, &As[cur ^ 1][c * 512]);
                GLL16(Wo + (long)(col0 + ar) * 512 + k0n + lk, &Bs[cur ^ 1][c * 512]);
            }
        }
        bf16x8 af[4], bfr[4];
#pragma unroll
        for (int mi = 0; mi < 4; ++mi)
            af[mi] = lds8(&As[cur][(wr * 64 + mi * 16 + (l & 15)) * 32 + (l >> 4) * 8]);
#pragma unroll
        for (int nj = 0; nj < 4; ++nj)
            bfr[nj] = lds8(&Bs[cur][(wc * 64 + nj * 16 + (l & 15)) * 32 + (l >> 4) * 8]);
#pragma unroll
        for (int mi = 0; mi < 4; ++mi)
#pragma unroll
            for (int nj = 0; nj < 4; ++nj)
                acc[mi][nj] = MFMA16(af[mi], bfr[nj], acc[mi][nj]);
        __syncthreads();
        cur ^= 1;
    }

    // park z (zero-padded to k=32) into As[0], then lora as one padded MFMA step
    {
        ushort8 zz = {0, 0, 0, 0, 0, 0, 0, 0};
        const int row = tid >> 1;
        if ((tid & 1) == 0) {
            *(ushort8*)&As[0][row * 32]     = *(const ushort8*)&zb[(row0 + row) * 8];
            *(ushort8*)&As[0][row * 32 + 8] = zz;
        } else {
            *(ushort8*)&As[0][row * 32 + 16] = zz;
            *(ushort8*)&As[0][row * 32 + 24] = zz;
        }
    }
    __syncthreads();

    const float* up = u + (long)bk * 4096;
#pragma unroll
    for (int nj = 0; nj < 4; ++nj) {
        const int og = col0 + wc * 64 + nj * 16 + (l & 15);
        ushort8 ubits = {0, 0, 0, 0, 0, 0, 0, 0};
        if ((l >> 4) == 0) {
            float4_t u0 = *(const float4_t*)(up + og * 8);
            float4_t u1 = *(const float4_t*)(up + og * 8 + 4);
            ubits[0] = f2bf(u0[0] * 0.125f); ubits[1] = f2bf(u0[1] * 0.125f);
            ubits[2] = f2bf(u0[2] * 0.125f); ubits[3] = f2bf(u0[3] * 0.125f);
            ubits[4] = f2bf(u1[0] * 0.125f); ubits[5] = f2bf(u1[1] * 0.125f);
            ubits[6] = f2bf(u1[2] * 0.125f); ubits[7] = f2bf(u1[3] * 0.125f);
        }
        bf16x8 ub = __builtin_bit_cast(bf16x8, ubits);
#pragma unroll
        for (int mi = 0; mi < 4; ++mi) {
            bf16x8 az = lds8(&As[0][(wr * 64 + mi * 16 + (l & 15)) * 32 + (l >> 4) * 8]);
            acc[mi][nj] = MFMA16(az, ub, acc[mi][nj]);
        }
    }

#pragma unroll
    for (int mi = 0; mi < 4; ++mi) {
        const long rb = row0 + wr * 64 + mi * 16 + (l >> 4) * 4;
#pragma unroll
        for (int nj = 0; nj < 4; ++nj) {
            const int og = col0 + wc * 64 + nj * 16 + (l & 15);
            const float badd = bo[og] + bb[bi * 512 + og];
#pragma unroll
            for (int q = 0; q < 4; ++q)
                Out[(rb + q) * 512 + og] = geluf(acc[mi][nj][q] + badd);
        }
    }
}

extern "C" void kernel_launch(void* const* d_in, const int* in_sizes, int n_in,
                              void* d_out, int out_size, void* d_ws, size_t ws_size,
                              hipStream_t stream) {
    const float* x  = (const float*)d_in[0];
    const float* u  = (const float*)d_in[1];
    const float* v  = (const float*)d_in[2];
    const float* bb = (const float*)d_in[3];
    const float* Wp = (const float*)d_in[4];
    const float* bp = (const float*)d_in[5];
    const float* Wa = (const float*)d_in[6];
    const float* ba = (const float*)d_in[7];
    const float* Wo = (const float*)d_in[8];
    const float* bo = (const float*)d_in[9];
    float* out = (float*)d_out;

    char* ws = (char*)d_ws;
    unsigned short* zb  = (unsigned short*)(ws + 0);         //  1 MB [65536][8]
    float*          xm  = (float*)(ws + 1048576);            // 16 MB [8192][512] fp32
    unsigned short* gy  = (unsigned short*)(ws + 17825792);  //  4 MB [8192][256]
    unsigned short* hp  = (unsigned short*)(ws + 22020096);  // 32 MB [65536][256]
    unsigned short* Wpb = (unsigned short*)(ws + 55574528);  // 256 KB
    unsigned short* Wab = (unsigned short*)(ws + 55836672);  // 256 KB
    unsigned short* Wob = (unsigned short*)(ws + 56098816);  // 512 KB (total ~54 MB)

    cvt_all<<<512, 256, 0, stream>>>(Wp, Wa, Wo, Wpb, Wab, Wob);
    // h_pass = gelu(x @ W_pass^T + b_pass): M=65536, reads x fp32 directly
    gemm_f32a<<<1024, 256, 0, stream>>>(x, Wpb, bp, hp, 128);
    // xm = mean_k(x)  (x is L3-warm from h_pass)
    mean_x<<<4096, 256, 0, stream>>>(x, xm);
    // gy = gelu(xm @ W_ave^T + b_ave): M=8192
    gemm_f32a<<<128, 256, 0, stream>>>(xm, Wab, ba, gy, 16);
    // z = (h . v)/512
    zcalc<<<512, 256, 0, stream>>>(hp, gy, v, zb);
    // out = gelu(h @ Wo^T + b_out + b + lora)
    gemm_out<<<2048, 256, 0, stream>>>(hp, gy, Wob, bo, bb, u, zb, out);
}